// Round 4
// baseline (1458.705 us; speedup 1.0000x reference)
//
#include <hip/hip_runtime.h>

// 5-layer GRU, H=20, B=256, T=4096, fp32. PyTorch GRU math.
// One block per batch element; 5 waves = one per layer. Pre-scaled weights
// (-log2e on r/z rows, -2log2e on n rows) so sigmoid/tanh need no leading
// multiply. Pairwise flag sync on depth-4 ring (no per-chunk __syncthreads).
//
// R8: ZERO DS ops on the recurrence chain.
//  (a) gate->lane remap: r rows -> lanes 0-19, z rows -> lanes 32-51,
//      n rows -> lanes 20-31 & 52-59. The z-sigmoid gather (lane i needs
//      lane i+32) is a cross-half permlane swap (VALU) instead of a
//      ds_bpermute (LDS round-trip, fully exposed on the serial chain).
//  (b) n-row h-projection computed IN the unit lane (second 10-pk_fma
//      matvec over W_hh rows 40+i) instead of gathered via ds_bpermute.
//  (c) #pragma unroll 4 on t-loops.
// R9 (failed): hand inline-asm v_permlane32_swap_b32 with "+v","+v" tied
// operands — two distinct wrong-zf signatures (0.33, 0.186) consistent with
// the asm's operand allocation not matching the intended dual-register
// swap. R10: use the OFFICIAL __builtin_amdgcn_permlane32_swap (verified on
// gfx950 by learn_hip T12/m214v22); it returns BOTH results as V2Ui and the
// compiler lowers the dual-write correctly. Keep (r0+r1)-v selection so the
// result is independent of which element is vdst vs vsrc.

#define HH 20
#define GG 60
#define NL 5
#define BB 256
#define TT 4096
#define KK 16
#define NC (TT / KK)
#define RD 4            // ring depth (chunks of drift allowed)

typedef float f2 __attribute__((ext_vector_type(2)));

struct Params {
  const float* x;
  const float* wih[NL];
  const float* whh[NL];
  const float* bih[NL];
  const float* bhh[NL];
  const float* wout;
  const float* bout;
  float* out;
};

__device__ __forceinline__ float bcast(float v, int j) {        // j: imm
  return __int_as_float(__builtin_amdgcn_readlane(__float_as_int(v), j));
}
__device__ __forceinline__ float bcast_dyn(float v, int j) {    // j: sgpr
  return __int_as_float(__builtin_amdgcn_readlane(__float_as_int(v), j));
}
// input pre-scaled by -log2e: sigmoid(x) = rcp(1 + exp2(x_scaled))
__device__ __forceinline__ float fsig_s(float xs) {
  return __builtin_amdgcn_rcpf(1.0f + __builtin_amdgcn_exp2f(xs));
}
// input pre-scaled by -2log2e: tanh(y) = 2*rcp(1 + exp2(y_scaled)) - 1
__device__ __forceinline__ float ftanh_s(float ys) {
  return fmaf(2.0f, __builtin_amdgcn_rcpf(1.0f + __builtin_amdgcn_exp2f(ys)), -1.0f);
}
// Cross-half fetch: lane i receives v[32+(i&31)] for i<32 (and v[i&31] for
// i>=32 — unused). The permlane32_swap builtin exchanges the low 32 lanes
// of arg0 with the high 32 lanes of arg1 and returns BOTH new values; with
// both args = v, the two results jointly hold {own-half, cross-half} in
// every lane, so (r0+r1)-v selects the cross-half value regardless of
// operand direction (rounding ~1e-7, negligible vs 1e-2 threshold).
__device__ __forceinline__ float zswap(float v) {
  auto r = __builtin_amdgcn_permlane32_swap(__float_as_uint(v), __float_as_uint(v),
                                            false, false);
  const float r0 = __uint_as_float(r[0]);
  const float r1 = __uint_as_float(r[1]);
  return (r0 + r1) - v;
}
__device__ __forceinline__ int ldv(const int* p) {
  return *(const volatile int*)p;
}

__global__ __launch_bounds__(NL * 64, 1) void gru5_kernel(Params p) {
  // ring: producer layer l (0..3) writes xring[l][c%RD]; consumer l+1 reads.
  // KK+1 rows so the consumer's t+1 prefetch is unguarded (row KK = junk).
  __shared__ float xring[NL - 1][RD][KK + 1][64];
  __shared__ float yp[NL];
  __shared__ int prog[NL - 1];   // chunks produced by layer l
  __shared__ int cons[NL - 1];   // chunks consumed by layer l+1

  const int tid = threadIdx.x;
  const int l = tid >> 6;          // wave index == layer
  const int lane = tid & 63;
  const int b = blockIdx.x;

  // gate-row owned by this lane (R8 remap):
  //   lanes  0-19 -> r rows  0-19
  //   lanes 32-51 -> z rows 20-39   (so z sits at unit_lane+32 for permlane)
  //   lanes 20-31 -> n rows 40-51, lanes 52-59 -> n rows 52-59
  int g;
  if (lane < 20)       g = lane;
  else if (lane < 32)  g = lane + 20;
  else if (lane < 52)  g = lane - 12;
  else if (lane < 60)  g = lane;
  else                 g = 59;
  // B-matvec row: the n row for this lane's unit (lanes 0-19); dup own row else
  const int gb = (lane < 20) ? 40 + lane : g;
  // ring read positions: own-row x-proj, and the n-row x-proj for unit lanes
  const int ri = lane;
  const int ni = (lane < 12) ? lane + 20 : (lane < 20 ? lane + 40 : 63);

  if (tid < NL - 1) { prog[tid] = 0; cons[tid] = 0; }

  const float S1 = -1.44269504088896f;   // -log2(e)      (r/z rows)
  const float S2 = -2.88539008177793f;   // -2*log2(e)    (n rows)
  const float scg = (g < 2 * HH) ? S1 : S2;

  // ---- weights into registers (packed pairs), pre-scaled ----
  f2 wA2[HH / 2];                // own gate row of W_hh
  f2 wB2[HH / 2];                // n row (40+unit) of W_hh, for unit lanes
  {
    const float* W = p.whh[l];
    #pragma unroll
    for (int j = 0; j < HH / 2; ++j) {
      wA2[j].x = W[g * HH + 2 * j]      * scg;
      wA2[j].y = W[g * HH + 2 * j + 1]  * scg;
      wB2[j].x = W[gb * HH + 2 * j]     * S2;
      wB2[j].y = W[gb * HH + 2 * j + 1] * S2;
    }
  }
  const float bnb = (lane < HH) ? p.bhh[l][gb] * S2 : 0.0f;   // b_hh_n

  f2 wnx2[HH / 2];
  float bnx = 0.0f;
  if (l < NL - 1) {
    const float* W = p.wih[l + 1];
    #pragma unroll
    for (int j = 0; j < HH / 2; ++j) {
      wnx2[j].x = W[g * HH + 2 * j]     * scg;
      wnx2[j].y = W[g * HH + 2 * j + 1] * scg;
    }
    bnx = (p.bih[l + 1][g] + (g < 2 * HH ? p.bhh[l + 1][g] : 0.0f)) * scg;
  } else {
    #pragma unroll
    for (int j = 0; j < HH / 2; ++j) { wnx2[j].x = 0.0f; wnx2[j].y = 0.0f; }
  }
  float w0own = 0.f, b0own = 0.f, w0n = 0.f, b0n = 0.f;
  if (l == 0) {
    w0own = p.wih[0][g] * scg;
    b0own = (p.bih[0][g] + (g < 2 * HH ? p.bhh[0][g] : 0.0f)) * scg;
    w0n = p.wih[0][gb] * S2;
    b0n = p.bih[0][gb] * S2;          // b_ih only (b_hh_n lives in bnb)
  }

  float hreg = 0.0f;               // lanes 0..19 carry h[unit]
  f2 hs2[HH / 2];                  // wave-uniform broadcast of h (SGPR pairs)
  #pragma unroll
  for (int j = 0; j < HH / 2; ++j) { hs2[j].x = 0.0f; hs2[j].y = 0.0f; }

  const float* xrow = p.x + (size_t)b * TT;
  float* hout = p.out + (size_t)b * TT * HH;

  // own-row hh matvec: scaled (W_hh h)[g]
  auto matvecA = [&]() -> float {
    f2 a0; a0.x = 0.0f; a0.y = 0.0f;
    f2 a1; a1.x = 0.0f; a1.y = 0.0f;
    #pragma unroll
    for (int j = 0; j < HH / 2; j += 2) {
      a0 = __builtin_elementwise_fma(wA2[j],     hs2[j],     a0);
      a1 = __builtin_elementwise_fma(wA2[j + 1], hs2[j + 1], a1);
    }
    f2 s = a0 + a1;
    return s.x + s.y;
  };
  // n-row hh matvec (+b_hh_n), valid in unit lanes — replaces the ghn gather
  auto matvecB = [&]() -> float {
    f2 a0; a0.x = bnb;  a0.y = 0.0f;
    f2 a1; a1.x = 0.0f; a1.y = 0.0f;
    #pragma unroll
    for (int j = 0; j < HH / 2; j += 2) {
      a0 = __builtin_elementwise_fma(wB2[j],     hs2[j],     a0);
      a1 = __builtin_elementwise_fma(wB2[j + 1], hs2[j + 1], a1);
    }
    f2 s = a0 + a1;
    return s.x + s.y;
  };
  auto refresh_hs = [&]() {
    #pragma unroll
    for (int j = 0; j < HH / 2; ++j) {
      hs2[j].x = bcast(hreg, 2 * j);
      hs2[j].y = bcast(hreg, 2 * j + 1);
    }
  };
  auto proj = [&]() -> float {     // next layer's xg value for this lane
    f2 c0; c0.x = bnx;  c0.y = 0.0f;
    f2 c1; c1.x = 0.0f; c1.y = 0.0f;
    #pragma unroll
    for (int j = 0; j < HH / 2; j += 2) {
      c0 = __builtin_elementwise_fma(wnx2[j],     hs2[j],     c0);
      c1 = __builtin_elementwise_fma(wnx2[j + 1], hs2[j + 1], c1);
    }
    f2 s = c0 + c1;
    return s.x + s.y;
  };
  // one GRU step: xr = own-row x-side preact (incl. biases), xn = n-row
  // x-side (incl. b_ih_n) for unit lanes. Entirely VALU — no DS on chain.
  auto gru_step = [&](float xr, float xn) {
    const float ghA = matvecA();
    const float ghB = matvecB();              // own-lane n h-proj (+b_hh_n)
    const float sv = xr + ghA;                // scaled preact (r or z row)
    const float sg = fsig_s(sv);              // r in unit lanes, z in z-lanes
    const float zf = zswap(sg);               // z for unit lanes (VALU!)
    const float n = ftanh_s(fmaf(sg, ghB, xn));
    hreg = fmaf(zf, hreg - n, n);             // (1-z)*n + z*h
  };

  __syncthreads();                 // flags initialized

  // prime layer-0 x stage for chunk 0 (lanes 0..KK-1 hold the chunk's x)
  float xstage = 0.0f;
  if (l == 0 && lane < KK) xstage = xrow[lane];

  for (int c = 0; c < NC; ++c) {
    // --- sync: wait for input chunk; backpressure on ring slot reuse ---
    if (l > 0) {
      while (ldv(&prog[l - 1]) < c + 1) __builtin_amdgcn_s_sleep(1);
    }
    if (l < NL - 1) {
      while (ldv(&cons[l]) < c + 1 - RD) __builtin_amdgcn_s_sleep(1);
    }

    if (l == 0) {
      float* dst = &xring[0][c & (RD - 1)][0][0];
      // prefetch next chunk's x (a whole chunk of latency to hide)
      float xnl = 0.0f;
      if (lane < KK && c + 1 < NC) xnl = xrow[(c + 1) * KK + lane];
      #pragma unroll 4
      for (int t = 0; t < KK; ++t) {
        const float xv = bcast_dyn(xstage, t);
        if (t > 0) dst[(t - 1) * 64 + lane] = proj();   // shadow: row t-1 (h(t-1))
        gru_step(fmaf(w0own, xv, b0own), fmaf(w0n, xv, b0n));
        refresh_hs();
      }
      dst[(KK - 1) * 64 + lane] = proj();         // flush last row before flag
      xstage = xnl;
    } else if (l < NL - 1) {
      const float* src = &xring[l - 1][c & (RD - 1)][0][0];
      float* dst = &xring[l][c & (RD - 1)][0][0];
      float xr_c = src[ri];
      float xn_c = src[ni];
      #pragma unroll 4
      for (int t = 0; t < KK; ++t) {
        const float* nsrc = src + (t + 1) * 64;   // row KK exists (junk, dead)
        const float xr_n = nsrc[ri];
        const float xn_n = nsrc[ni];
        if (t > 0) dst[(t - 1) * 64 + lane] = proj();
        gru_step(xr_c, xn_c);
        refresh_hs();
        xr_c = xr_n; xn_c = xn_n;
      }
      dst[(KK - 1) * 64 + lane] = proj();
    } else {
      const float* src = &xring[NL - 2][c & (RD - 1)][0][0];
      float* hp = hout + (size_t)c * KK * HH;
      float xr_c = src[ri];
      float xn_c = src[ni];
      #pragma unroll 4
      for (int t = 0; t < KK; ++t) {
        const float* nsrc = src + (t + 1) * 64;
        const float xr_n = nsrc[ri];
        const float xn_n = nsrc[ni];
        if (t > 0 && lane < HH) hp[(t - 1) * HH + lane] = hreg;  // h(t-1)
        gru_step(xr_c, xn_c);
        refresh_hs();                       // keeps hs fresh for next iter
        xr_c = xr_n; xn_c = xn_n;
      }
      if (lane < HH) hp[(KK - 1) * HH + lane] = hreg;
    }

    // --- publish: producer flags chunk done; consumer frees ring slot ---
    if (l < NL - 1) {
      __threadfence_block();               // drain LDS writes before flag
      if (lane == 0) *(volatile int*)&prog[l] = c + 1;
    }
    if (l > 0) {
      if (lane == 0) *(volatile int*)&cons[l - 1] = c + 1;
    }
  }

  // ---- epilogue: h_n + y_hat partial (per wave, then one final barrier) ----
  if (lane < HH)
    p.out[(size_t)BB * TT * HH + (size_t)b * NL * HH + l * HH + lane] = hreg;
  float pp = (lane < HH) ? hreg * p.wout[l * HH + lane] : 0.0f;
  #pragma unroll
  for (int off = 32; off > 0; off >>= 1) pp += __shfl_down(pp, off);
  if (lane == 0) yp[l] = pp;

  __syncthreads();
  if (tid == 0) {
    float y = p.bout[0];
    #pragma unroll
    for (int ll = 0; ll < NL; ++ll) y += yp[ll];
    p.out[(size_t)BB * TT * HH + (size_t)BB * NL * HH + b] = y;
  }
}

extern "C" void kernel_launch(void* const* d_in, const int* in_sizes, int n_in,
                              void* d_out, int out_size, void* d_ws, size_t ws_size,
                              hipStream_t stream) {
  Params p;
  p.x = (const float*)d_in[0];
  for (int l = 0; l < NL; ++l) {
    p.wih[l] = (const float*)d_in[1 + 4 * l];
    p.whh[l] = (const float*)d_in[2 + 4 * l];
    p.bih[l] = (const float*)d_in[3 + 4 * l];
    p.bhh[l] = (const float*)d_in[4 + 4 * l];
  }
  p.wout = (const float*)d_in[1 + 4 * NL];
  p.bout = (const float*)d_in[2 + 4 * NL];
  p.out = (float*)d_out;

  gru5_kernel<<<BB, NL * 64, 0, stream>>>(p);
}